// Round 3
// baseline (290.397 us; speedup 1.0000x reference)
//
#include <hip/hip_runtime.h>

typedef __attribute__((ext_vector_type(8))) short bf16x8;
typedef __attribute__((ext_vector_type(4))) float f32x4;

#define LOG2E 1.44269504088896340736f

// Average-trace constant from the Python module (length 120).
__device__ __constant__ float AVG_D[120] = {
    0.0256f,0.0823f,0.1157f,0.1315f,0.1366f,0.1369f,0.1347f,0.1308f,0.1259f,0.1205f,
    0.1146f,0.1086f,0.1028f,0.0970f,0.0913f,0.0858f,0.0805f,0.0756f,0.0708f,0.0664f,
    0.0623f,0.0584f,0.0549f,0.0515f,0.0485f,0.0456f,0.0429f,0.0404f,0.0381f,0.0360f,
    0.0340f,0.0321f,0.0304f,0.0287f,0.0272f,0.0258f,0.0245f,0.0233f,0.0222f,0.0211f,
    0.0201f,0.0191f,0.0182f,0.0173f,0.0165f,0.0158f,0.0150f,0.0143f,0.0137f,0.0130f,
    0.0125f,0.0119f,0.0114f,0.0108f,0.0104f,0.0099f,0.0095f,0.0091f,0.0087f,0.0083f,
    0.0080f,0.0077f,0.0074f,0.0071f,0.0068f,0.0065f,0.0062f,0.0060f,0.0058f,0.0055f,
    0.0053f,0.0050f,0.0049f,0.0047f,0.0045f,0.0044f,0.0042f,0.0040f,0.0039f,0.0038f,
    0.0036f,0.0034f,0.0033f,0.0032f,0.0031f,0.0030f,0.0029f,0.0028f,0.0027f,0.0026f,
    0.0025f,0.0024f,0.0023f,0.0022f,0.0021f,0.0021f,0.0020f,0.0019f,0.0018f,0.0018f,
    0.0017f,0.0017f,0.0016f,0.0016f,0.0015f,0.0015f,0.0014f,0.0014f,0.0013f,0.0013f,
    0.0013f,0.0012f,0.0012f,0.0011f,0.0011f,0.0011f,0.0010f,0.0010f,0.0010f,0.0009f
};

__device__ __forceinline__ float sig2(float x) {
    return __builtin_amdgcn_rcpf(1.0f + __builtin_amdgcn_exp2f(x));
}
__device__ __forceinline__ float tanh2(float x) {
    return fmaf(2.0f, __builtin_amdgcn_rcpf(1.0f + __builtin_amdgcn_exp2f(x)), -1.0f);
}
__device__ __forceinline__ unsigned short tb(float x) {          // truncate fp32 -> bf16
    return (unsigned short)(__float_as_uint(x) >> 16);
}
__device__ __forceinline__ float fb(unsigned short h) {
    return __uint_as_float(((unsigned)h) << 16);
}

// Cross-lane butterfly primitives (gfx950): both outputs are live.
// v_permlane32_swap: a'[32+i]=b[i], b'[i]=a[32+i]  (exchanges lane bit 5)
// v_permlane16_swap: exchanges lane bit 4 halves   (bits 0-3 preserved)
__device__ __forceinline__ void swap32(unsigned &a, unsigned &b) {
    auto r = __builtin_amdgcn_permlane32_swap(a, b, false, false);
    a = r[0]; b = r[1];
}
__device__ __forceinline__ void swap16(unsigned &a, unsigned &b) {
    auto r = __builtin_amdgcn_permlane16_swap(a, b, false, false);
    a = r[0]; b = r[1];
}

// A[128 rows][32 k], row r = u*4+q, PRE-SCALED by sc(q) = -log2e (i,f,o) / -2log2e (g):
//   u<30,  k<30 : sc*W_hh1[(q*30+u)*30+k]
//   u<30,  k==30: sc*W_ih1[(q*30+u)*13+12]   (avg column; B k=30 slot = AVG[t])
//   u==30, k<30 : sc*W_ih2[q*30+k]           (LSTM2 input dot rides the same MFMA)
// ws layout (float*): ushort whi[4096] @0; ushort wlo @2048; float bconst[128] @4096
//                     float wih1f[128*12] @4224; u32 avgpk[121] @5760 (hi|lo<<16)
__global__ void pack_weights(const float* __restrict__ w_ih1,
                             const float* __restrict__ w_hh1,
                             const float* __restrict__ b1,
                             const float* __restrict__ w_ih2,
                             const float* __restrict__ b2,
                             float* __restrict__ ws) {
    unsigned short* whi = (unsigned short*)ws;
    unsigned short* wlo = (unsigned short*)(ws + 2048);
    float* bconst = ws + 4096;
    float* wih1f  = ws + 4224;
    unsigned* avgpk = (unsigned*)(ws + 5760);
    const int tid = threadIdx.x;
    for (int idx = tid; idx < 4096; idx += 256) {
        const int T = idx >> 9, lane = (idx >> 3) & 63, j = idx & 7;
        const int r = 16 * T + (lane & 15);
        const int k = ((lane >> 4) & 3) * 8 + j;
        const int u = r >> 2, q = r & 3;
        const float sc = (q == 2) ? (-2.0f * LOG2E) : (-LOG2E);
        float v = 0.0f;
        if (u < 30) {
            if (k < 30)       v = w_hh1[(q * 30 + u) * 30 + k];
            else if (k == 30) v = w_ih1[(q * 30 + u) * 13 + 12];
        } else if (u == 30 && k < 30) {
            v = w_ih2[q * 30 + k];
        }
        v *= sc;
        const unsigned short hi = tb(v);
        whi[idx] = hi;
        wlo[idx] = tb(v - fb(hi));
    }
    for (int r = tid; r < 128; r += 256) {
        const int u = r >> 2, q = r & 3;
        const float sc = (q == 2) ? (-2.0f * LOG2E) : (-LOG2E);
        bconst[r] = sc * ((u < 30) ? b1[q * 30 + u] : ((u == 30) ? b2[q] : 0.0f));
    }
    for (int idx = tid; idx < 1536; idx += 256) {
        const int r = idx / 12, d = idx % 12;
        const int u = r >> 2, q = r & 3;
        const float sc = (q == 2) ? (-2.0f * LOG2E) : (-LOG2E);
        wih1f[idx] = (u < 30) ? sc * w_ih1[(q * 30 + u) * 13 + d] : 0.0f;
    }
    for (int t = tid; t < 121; t += 256) {
        const float a = (t < 120) ? AVG_D[t] : 0.0f;
        const unsigned short hi = tb(a);
        const unsigned short lo = tb(a - fb(hi));
        avgpk[t] = (unsigned)hi | ((unsigned)lo << 16);
    }
}

// Block = 128 threads = 2 INDEPENDENT waves; each wave owns ALL 128 A-rows
// (8 tiles) for its own 16 sequences.
//
// R7/R8/R9: h state never touches LDS. Lane (s,quad) produces h for units
// u=4T+quad (packed hi|lo<<16 bf16 in hpk[T]); the next step's B fragment
// needs units 8*quad+j for the same s — a 4x4 transpose of PAIRS across the
// quad dim (lane bits 4,5). Done in-register with 2 butterfly stages:
//   permlane32_swap (bit5) then permlane16_swap (bit4), even pair-set
//   {hpk[0],2,4,6} -> Bv[0..3], odd set {hpk[1],3,5,7} -> Bv[4..7].
// Static proof: initially e_i@quad q = h[8i+q]; stage1 swaps (reg-bit1,
// lane-bit5), stage2 swaps (reg-bit0, lane-bit4) -> e_i@q = h[8q+i]. Lane
// bits 0-3 (s) preserved by both ops. AVG slot (unit30) / zero pad (unit31)
// land on quad3 o2/o3 and are patched there — same slots the LDS build
// patched. This removes the per-step DS round-trip (2x ds_read_b128 +
// 8x ds_write_b32 + lgkmcnt) from the serial recurrence chain — the kernel
// runs 2 waves/SIMD (structural: 32768/16) so that latency was unhidden.
// avgpk[t+1] is prefetched one full iteration ahead (apk_cur) so the uniform
// load is never on the serial chain.
__global__ __launch_bounds__(128, 2)
void lstm_mfma_kernel(const float* __restrict__ feat,
                      const float* __restrict__ w_hh2,
                      const float* __restrict__ ws,
                      float* __restrict__ out) {
    __shared__ __align__(16) float out_s[32 * 124];      // h2 staging, 15.9 KB

    const int tid  = threadIdx.x;
    const int lane = tid & 63;
    const int wv   = __builtin_amdgcn_readfirstlane(tid >> 6);
    const int s    = lane & 15;
    const int quad = lane >> 4;
    const int seq  = blockIdx.x * 32 + wv * 16 + s;
    const unsigned* avgpk = (const unsigned*)(ws + 5760);

    // ---- A fragments (pre-scaled, exact hi/lo split), all 8 tiles ----
    bf16x8 Ahi[8], Alo[8];
    {
        const unsigned short* whi = (const unsigned short*)ws;
        const unsigned short* wlo = (const unsigned short*)(ws + 2048);
#pragma unroll
        for (int T = 0; T < 8; T++) {
            Ahi[T] = *(const bf16x8*)(whi + T * 512 + lane * 8);
            Alo[T] = *(const bf16x8*)(wlo + T * 512 + lane * 8);
        }
    }

    // ---- per-sequence constant projection (scaled domain), 8 tiles ----
    float f0[12];
    {
        const float4* fp = reinterpret_cast<const float4*>(feat + seq * 12);
        float4 A = fp[0], B = fp[1], C = fp[2];
        f0[0]=A.x; f0[1]=A.y; f0[2]=A.z; f0[3]=A.w;
        f0[4]=B.x; f0[5]=B.y; f0[6]=B.z; f0[7]=B.w;
        f0[8]=C.x; f0[9]=C.y; f0[10]=C.z; f0[11]=C.w;
    }
    f32x4 projb[8];
    {
        const float* bconst = ws + 4096;
        const float* wih1f  = ws + 4224;
#pragma unroll
        for (int T = 0; T < 8; T++) {
#pragma unroll
            for (int g = 0; g < 4; g++) {
                const int r = 16 * T + 4 * quad + g;
                float acc = bconst[r];
#pragma unroll
                for (int d = 0; d < 12; d++) acc = fmaf(f0[d], wih1f[r * 12 + d], acc);
                projb[T][g] = acc;
            }
        }
    }

    float c1[8];
#pragma unroll
    for (int T = 0; T < 8; T++) c1[T] = 0.0f;
    float h2 = 0.0f, c2 = 0.0f;
    const float whs0 = -LOG2E * w_hh2[0];
    const float whs1 = -LOG2E * w_hh2[1];
    const float whs2 = -2.0f * LOG2E * w_hh2[2];
    const float whs3 = -LOG2E * w_hh2[3];

    // ---- loop-carried B state (registers): h_{t-1} packed + AVG/zero slots ----
    unsigned e0 = 0u, e1 = 0u, e2 = 0u, e3 = 0u;   // Bv[0..3]: units 8q+0..3
    unsigned o0 = 0u, o1 = 0u, o2 = 0u, o3 = 0u;   // Bv[4..7]: units 8q+4..7
    if (quad == 3) o2 = avgpk[0];                  // unit 30 slot = AVG[0]
    union { int4 i; bf16x8 v; } ubh, ubl;
#define BUILD_B() do {                                                  \
        ubh.i.x = (int)__builtin_amdgcn_perm(e1, e0, 0x05040100u);      \
        ubh.i.y = (int)__builtin_amdgcn_perm(e3, e2, 0x05040100u);      \
        ubh.i.z = (int)__builtin_amdgcn_perm(o1, o0, 0x05040100u);      \
        ubh.i.w = (int)__builtin_amdgcn_perm(o3, o2, 0x05040100u);      \
        ubl.i.x = (int)__builtin_amdgcn_perm(e1, e0, 0x07060302u);      \
        ubl.i.y = (int)__builtin_amdgcn_perm(e3, e2, 0x07060302u);      \
        ubl.i.z = (int)__builtin_amdgcn_perm(o1, o0, 0x07060302u);      \
        ubl.i.w = (int)__builtin_amdgcn_perm(o3, o2, 0x07060302u);      \
    } while (0)
    BUILD_B();

    unsigned apk_cur = avgpk[1];   // AVG slot value for the t=0 update

#pragma unroll 1
    for (int t = 0; t <= 120; t++) {
        const bf16x8 Bhi = ubh.v, Blo = ubl.v;

        // prefetch next AVG word a full iteration early (off the serial chain)
        const unsigned apk = apk_cur;
        apk_cur = avgpk[(t + 2 <= 120) ? (t + 2) : 120];

        // ---- 24 MFMAs: D = Ahi*Bhi + Ahi*Blo + Alo*Bhi + projb ----
        f32x4 D[8];
#pragma unroll
        for (int T = 0; T < 8; T++)
            D[T] = __builtin_amdgcn_mfma_f32_16x16x32_bf16(Alo[T], Bhi, projb[T], 0, 0, 0);
#pragma unroll
        for (int T = 0; T < 8; T++)
            D[T] = __builtin_amdgcn_mfma_f32_16x16x32_bf16(Ahi[T], Blo, D[T], 0, 0, 0);
#pragma unroll
        for (int T = 0; T < 8; T++)
            D[T] = __builtin_amdgcn_mfma_f32_16x16x32_bf16(Ahi[T], Bhi, D[T], 0, 0, 0);

        // ---- LSTM2 cell for step t-1 (tile7 rows 120..123, quad==2 lanes) ----
        if (t >= 1 && quad == 2) {
            const float g0 = fmaf(h2, whs0, D[7][0]);
            const float g1 = fmaf(h2, whs1, D[7][1]);
            const float g2 = fmaf(h2, whs2, D[7][2]);
            const float g3 = fmaf(h2, whs3, D[7][3]);
            c2 = sig2(g1) * c2 + sig2(g0) * tanh2(g2);
            h2 = sig2(g3) * tanh2(c2 * (-2.0f * LOG2E));
            out_s[(wv * 16 + s) * 124 + (t - 1)] = h2;
        }

        // ---- LSTM1 fused activations (u=4T+quad); pack bf16 h_t in regs ----
        if (t < 120) {
            unsigned hpk[8];
#pragma unroll
            for (int T = 0; T < 8; T++) {
                const int u = 4 * T + quad;
                unsigned v = 0u;
                if (u < 30) {
                    const float ei = __builtin_amdgcn_exp2f(D[T][0]);
                    const float ef = __builtin_amdgcn_exp2f(D[T][1]);
                    const float eg = __builtin_amdgcn_exp2f(D[T][2]);
                    const float eo = __builtin_amdgcn_exp2f(D[T][3]);
                    const float pi_ = 1.0f + ei, pf = 1.0f + ef;
                    const float pg  = 1.0f + eg, po = 1.0f + eo;
                    const float pig = pi_ * pg;
                    const float num = fmaf(c1[T], pig, (1.0f - eg) * pf);
                    const float ck  = num * __builtin_amdgcn_rcpf(pf * pig);
                    c1[T] = ck;
                    float carg = -2.0f * LOG2E * ck;
                    carg = fminf(fmaxf(carg, -80.0f), 80.0f);
                    const float ec = __builtin_amdgcn_exp2f(carg);
                    const float hk = (1.0f - ec) *
                                     __builtin_amdgcn_rcpf(po * (1.0f + ec));
                    const unsigned hbits = __float_as_uint(hk);
                    const float rem = hk - __uint_as_float(hbits & 0xffff0000u);
                    v = __builtin_amdgcn_perm(__float_as_uint(rem), hbits, 0x07060302u);
                }
                hpk[T] = v;
            }

            // ---- in-register quad transpose: hpk -> next B values ----
            // even pair-set -> Bv[0..3], odd pair-set -> Bv[4..7]
            e0 = hpk[0]; e1 = hpk[2]; e2 = hpk[4]; e3 = hpk[6];
            o0 = hpk[1]; o1 = hpk[3]; o2 = hpk[5]; o3 = hpk[7];
            swap32(e0, e2); swap32(e1, e3);   // butterfly on lane bit5
            swap16(e0, e1); swap16(e2, e3);   // butterfly on lane bit4
            swap32(o0, o2); swap32(o1, o3);
            swap16(o0, o1); swap16(o2, o3);
            if (quad == 3) { o2 = apk; o3 = 0u; }  // unit30=AVG[t+1], unit31=0
            BUILD_B();
        }
        // no barrier, no LDS: recurrence is fully lane/register-local per wave
    }

    __syncthreads();
    // ---- coalesced flush: 32 seq x 120 t = 960 float4 by 128 threads ----
    float* outb = out + (size_t)blockIdx.x * 32 * 120;
#pragma unroll
    for (int it = 0; it < 8; it++) {
        const int fi = it * 128 + tid;
        if (fi < 960) {
            const int sq = fi / 30, j = fi % 30;
            const float4 v = *reinterpret_cast<const float4*>(&out_s[sq * 124 + j * 4]);
            *reinterpret_cast<float4*>(&outb[sq * 120 + j * 4]) = v;
        }
    }
}

extern "C" void kernel_launch(void* const* d_in, const int* in_sizes, int n_in,
                              void* d_out, int out_size, void* d_ws, size_t ws_size,
                              hipStream_t stream) {
    (void)in_sizes; (void)n_in; (void)out_size; (void)ws_size;
    const float* feat  = (const float*)d_in[0];
    const float* w_ih1 = (const float*)d_in[1];
    const float* w_hh1 = (const float*)d_in[2];
    const float* b1    = (const float*)d_in[3];
    const float* w_ih2 = (const float*)d_in[4];
    const float* w_hh2 = (const float*)d_in[5];
    const float* b2    = (const float*)d_in[6];
    float* ws  = (float*)d_ws;
    float* out = (float*)d_out;

    hipLaunchKernelGGL(pack_weights, dim3(1), dim3(256), 0, stream,
                       w_ih1, w_hh1, b1, w_ih2, b2, ws);
    hipLaunchKernelGGL(lstm_mfma_kernel, dim3(1024), dim3(128), 0, stream,
                       feat, w_hh2, ws, out);
}

// Round 5
// 257.253 us; speedup vs baseline: 1.1288x; 1.1288x over previous
//
#include <hip/hip_runtime.h>

typedef __attribute__((ext_vector_type(8))) short bf16x8;
typedef __attribute__((ext_vector_type(4))) float f32x4;

#define LOG2E 1.44269504088896340736f

// Average-trace constant from the Python module (length 120).
__device__ __constant__ float AVG_D[120] = {
    0.0256f,0.0823f,0.1157f,0.1315f,0.1366f,0.1369f,0.1347f,0.1308f,0.1259f,0.1205f,
    0.1146f,0.1086f,0.1028f,0.0970f,0.0913f,0.0858f,0.0805f,0.0756f,0.0708f,0.0664f,
    0.0623f,0.0584f,0.0549f,0.0515f,0.0485f,0.0456f,0.0429f,0.0404f,0.0381f,0.0360f,
    0.0340f,0.0321f,0.0304f,0.0287f,0.0272f,0.0258f,0.0245f,0.0233f,0.0222f,0.0211f,
    0.0201f,0.0191f,0.0182f,0.0173f,0.0165f,0.0158f,0.0150f,0.0143f,0.0137f,0.0130f,
    0.0125f,0.0119f,0.0114f,0.0108f,0.0104f,0.0099f,0.0095f,0.0091f,0.0087f,0.0083f,
    0.0080f,0.0077f,0.0074f,0.0071f,0.0068f,0.0065f,0.0062f,0.0060f,0.0058f,0.0055f,
    0.0053f,0.0050f,0.0049f,0.0047f,0.0045f,0.0044f,0.0042f,0.0040f,0.0039f,0.0038f,
    0.0036f,0.0034f,0.0033f,0.0032f,0.0031f,0.0030f,0.0029f,0.0028f,0.0027f,0.0026f,
    0.0025f,0.0024f,0.0023f,0.0022f,0.0021f,0.0021f,0.0020f,0.0019f,0.0018f,0.0018f,
    0.0017f,0.0017f,0.0016f,0.0016f,0.0015f,0.0015f,0.0014f,0.0014f,0.0013f,0.0013f,
    0.0013f,0.0012f,0.0012f,0.0011f,0.0011f,0.0011f,0.0010f,0.0010f,0.0010f,0.0009f
};

__device__ __forceinline__ float sig2(float x) {
    return __builtin_amdgcn_rcpf(1.0f + __builtin_amdgcn_exp2f(x));
}
__device__ __forceinline__ float tanh2(float x) {
    return fmaf(2.0f, __builtin_amdgcn_rcpf(1.0f + __builtin_amdgcn_exp2f(x)), -1.0f);
}
__device__ __forceinline__ unsigned short tb(float x) {          // truncate fp32 -> bf16
    return (unsigned short)(__float_as_uint(x) >> 16);
}
__device__ __forceinline__ float fb(unsigned short h) {
    return __uint_as_float(((unsigned)h) << 16);
}

// A[128 rows][32 k], row r = u*4+q, PRE-SCALED by sc(q) = -log2e (i,f,o) / -2log2e (g):
//   u<30,  k<30 : sc*W_hh1[(q*30+u)*30+k]
//   u<30,  k==30: sc*W_ih1[(q*30+u)*13+12]   (avg column; B k=30 slot = AVG[t])
//   u==30, k<30 : sc*W_ih2[q*30+k]           (LSTM2 input dot rides the same MFMA)
// ws layout (float*): ushort whi[4096] @0; ushort wlo @2048; float bconst[128] @4096
//                     float wih1f[128*12] @4224; u32 avgpk[121] @5760 (hi|lo<<16)
__global__ void pack_weights(const float* __restrict__ w_ih1,
                             const float* __restrict__ w_hh1,
                             const float* __restrict__ b1,
                             const float* __restrict__ w_ih2,
                             const float* __restrict__ b2,
                             float* __restrict__ ws) {
    unsigned short* whi = (unsigned short*)ws;
    unsigned short* wlo = (unsigned short*)(ws + 2048);
    float* bconst = ws + 4096;
    float* wih1f  = ws + 4224;
    unsigned* avgpk = (unsigned*)(ws + 5760);
    const int tid = threadIdx.x;
    for (int idx = tid; idx < 4096; idx += 256) {
        const int T = idx >> 9, lane = (idx >> 3) & 63, j = idx & 7;
        const int r = 16 * T + (lane & 15);
        const int k = ((lane >> 4) & 3) * 8 + j;
        const int u = r >> 2, q = r & 3;
        const float sc = (q == 2) ? (-2.0f * LOG2E) : (-LOG2E);
        float v = 0.0f;
        if (u < 30) {
            if (k < 30)       v = w_hh1[(q * 30 + u) * 30 + k];
            else if (k == 30) v = w_ih1[(q * 30 + u) * 13 + 12];
        } else if (u == 30 && k < 30) {
            v = w_ih2[q * 30 + k];
        }
        v *= sc;
        const unsigned short hi = tb(v);
        whi[idx] = hi;
        wlo[idx] = tb(v - fb(hi));
    }
    for (int r = tid; r < 128; r += 256) {
        const int u = r >> 2, q = r & 3;
        const float sc = (q == 2) ? (-2.0f * LOG2E) : (-LOG2E);
        bconst[r] = sc * ((u < 30) ? b1[q * 30 + u] : ((u == 30) ? b2[q] : 0.0f));
    }
    for (int idx = tid; idx < 1536; idx += 256) {
        const int r = idx / 12, d = idx % 12;
        const int u = r >> 2, q = r & 3;
        const float sc = (q == 2) ? (-2.0f * LOG2E) : (-LOG2E);
        wih1f[idx] = (u < 30) ? sc * w_ih1[(q * 30 + u) * 13 + d] : 0.0f;
    }
    for (int t = tid; t < 121; t += 256) {
        const float a = (t < 120) ? AVG_D[t] : 0.0f;
        const unsigned short hi = tb(a);
        const unsigned short lo = tb(a - fb(hi));
        avgpk[t] = (unsigned)hi | ((unsigned)lo << 16);
    }
}

// R10/R11: OCCUPANCY restructure. rocprof @R8-register-kernel: Occupancy 21%
// (2 waves/SIMD structural), VALUBusy 60%, MfmaUtil 17.6% — ~40% of cycles
// are dependency stalls nothing can fill. Fix: split the 128 A-rows across
// 2 COOPERATING waves per block (wave w owns tiles Tg=4w..4w+3 = units
// 16w..16w+15; wave1 owns the LSTM2 row u=30). Each step the waves exchange
// h halves through a double-buffered LDS buffer (R6-proven layout: u32
// packed hi|lo<<16 at hx[buf][s*36+u]) with ONE __syncthreads per step.
// Grid 2048 blocks x 2 waves = 4096 waves = 4 waves/SIMD (was 2). Per-wave
// state halves -> fits the 128-VGPR cap for 4 waves/EU. LDS 12.5 KB/block,
// 8 blocks/CU = 100 KB. Per-SIMD work/step unchanged; stall fraction drops.
__global__ __launch_bounds__(128, 4)
void lstm_mfma_kernel(const float* __restrict__ feat,
                      const float* __restrict__ w_hh2,
                      const float* __restrict__ ws,
                      float* __restrict__ out) {
    __shared__ __align__(16) unsigned hx[2][16 * 36];  // 4.6 KB, double-buffered h
    __shared__ __align__(16) float out_s[16 * 124];    // h2 staging, 7.9 KB

    const int tid  = threadIdx.x;
    const int lane = tid & 63;
    const int wv   = __builtin_amdgcn_readfirstlane(tid >> 6);
    const int s    = lane & 15;
    const int quad = lane >> 4;
    const int seq  = blockIdx.x * 16 + s;
    const unsigned* avgpk = (const unsigned*)(ws + 5760);

    // zero both h buffers (pads stay 0), then seed AVG[0] in buf0
    for (int i = tid; i < 2 * 16 * 36; i += 128) (&hx[0][0])[i] = 0u;
    __syncthreads();
    if (tid < 16) hx[0][tid * 36 + 30] = avgpk[0];

    // ---- A fragments: this wave's 4 tiles (Tg = 4*wv + T) ----
    bf16x8 Ahi[4], Alo[4];
    {
        const unsigned short* whi = (const unsigned short*)ws;
        const unsigned short* wlo = (const unsigned short*)(ws + 2048);
#pragma unroll
        for (int T = 0; T < 4; T++) {
            const int Tg = 4 * wv + T;
            Ahi[T] = *(const bf16x8*)(whi + Tg * 512 + lane * 8);
            Alo[T] = *(const bf16x8*)(wlo + Tg * 512 + lane * 8);
        }
    }

    // ---- per-sequence constant projection (scaled domain), 4 tiles ----
    float f0[12];
    {
        const float4* fp = reinterpret_cast<const float4*>(feat + seq * 12);
        float4 A = fp[0], B = fp[1], C = fp[2];
        f0[0]=A.x; f0[1]=A.y; f0[2]=A.z; f0[3]=A.w;
        f0[4]=B.x; f0[5]=B.y; f0[6]=B.z; f0[7]=B.w;
        f0[8]=C.x; f0[9]=C.y; f0[10]=C.z; f0[11]=C.w;
    }
    f32x4 projb[4];
    {
        const float* bconst = ws + 4096;
        const float* wih1f  = ws + 4224;
#pragma unroll
        for (int T = 0; T < 4; T++) {
#pragma unroll
            for (int g = 0; g < 4; g++) {
                const int r = 16 * (4 * wv + T) + 4 * quad + g;
                float acc = bconst[r];
#pragma unroll
                for (int d = 0; d < 12; d++) acc = fmaf(f0[d], wih1f[r * 12 + d], acc);
                projb[T][g] = acc;
            }
        }
    }

    float c1[4];
#pragma unroll
    for (int T = 0; T < 4; T++) c1[T] = 0.0f;
    float h2 = 0.0f, c2 = 0.0f;
    const float whs0 = -LOG2E * w_hh2[0];
    const float whs1 = -LOG2E * w_hh2[1];
    const float whs2 = -2.0f * LOG2E * w_hh2[2];
    const float whs3 = -LOG2E * w_hh2[3];

    __syncthreads();   // AVG seed visible to both waves

    unsigned apk_cur = avgpk[1];   // AVG slot value for the t=0 update

#pragma unroll 1
    for (int t = 0; t <= 120; t++) {
        const unsigned* hb = hx[t & 1];
        unsigned*       hn = hx[(t & 1) ^ 1];

        // prefetch next AVG word a full iteration early (off the serial chain)
        const unsigned apk = apk_cur;
        apk_cur = avgpk[(t + 2 <= 120) ? (t + 2) : 120];

        // ---- B fragment: 2 ds_read_b128 + 8 perms (units 8q..8q+7, seq s) ----
        const uint4 Ra = *reinterpret_cast<const uint4*>(hb + s * 36 + 8 * quad);
        const uint4 Rb = *reinterpret_cast<const uint4*>(hb + s * 36 + 8 * quad + 4);
        union { int4 i; bf16x8 v; } ubh, ubl;
        ubh.i.x = (int)__builtin_amdgcn_perm(Ra.y, Ra.x, 0x05040100u);
        ubh.i.y = (int)__builtin_amdgcn_perm(Ra.w, Ra.z, 0x05040100u);
        ubh.i.z = (int)__builtin_amdgcn_perm(Rb.y, Rb.x, 0x05040100u);
        ubh.i.w = (int)__builtin_amdgcn_perm(Rb.w, Rb.z, 0x05040100u);
        ubl.i.x = (int)__builtin_amdgcn_perm(Ra.y, Ra.x, 0x07060302u);
        ubl.i.y = (int)__builtin_amdgcn_perm(Ra.w, Ra.z, 0x07060302u);
        ubl.i.z = (int)__builtin_amdgcn_perm(Rb.y, Rb.x, 0x07060302u);
        ubl.i.w = (int)__builtin_amdgcn_perm(Rb.w, Rb.z, 0x07060302u);
        const bf16x8 Bhi = ubh.v, Blo = ubl.v;

        // ---- 12 MFMAs: D = Ahi*Bhi + Ahi*Blo + Alo*Bhi + projb ----
        f32x4 D[4];
#pragma unroll
        for (int T = 0; T < 4; T++)
            D[T] = __builtin_amdgcn_mfma_f32_16x16x32_bf16(Alo[T], Bhi, projb[T], 0, 0, 0);
#pragma unroll
        for (int T = 0; T < 4; T++)
            D[T] = __builtin_amdgcn_mfma_f32_16x16x32_bf16(Ahi[T], Blo, D[T], 0, 0, 0);
#pragma unroll
        for (int T = 0; T < 4; T++)
            D[T] = __builtin_amdgcn_mfma_f32_16x16x32_bf16(Ahi[T], Bhi, D[T], 0, 0, 0);

        // ---- LSTM2 cell for step t-1 (wave1 local tile3 = rows 120..123) ----
        if (wv == 1 && t >= 1 && quad == 2) {
            const float g0 = fmaf(h2, whs0, D[3][0]);
            const float g1 = fmaf(h2, whs1, D[3][1]);
            const float g2 = fmaf(h2, whs2, D[3][2]);
            const float g3 = fmaf(h2, whs3, D[3][3]);
            c2 = sig2(g1) * c2 + sig2(g0) * tanh2(g2);
            h2 = sig2(g3) * tanh2(c2 * (-2.0f * LOG2E));
            out_s[s * 124 + (t - 1)] = h2;
        }

        // ---- LSTM1 activations (u=16wv+4T+quad); write packed bf16 h_t ----
        if (t < 120) {
#pragma unroll
            for (int T = 0; T < 4; T++) {
                const int u = 16 * wv + 4 * T + quad;
                unsigned v = 0u;
                if (u < 30) {
                    const float ei = __builtin_amdgcn_exp2f(D[T][0]);
                    const float ef = __builtin_amdgcn_exp2f(D[T][1]);
                    const float eg = __builtin_amdgcn_exp2f(D[T][2]);
                    const float eo = __builtin_amdgcn_exp2f(D[T][3]);
                    const float pi_ = 1.0f + ei, pf = 1.0f + ef;
                    const float pg  = 1.0f + eg, po = 1.0f + eo;
                    const float pig = pi_ * pg;
                    const float num = fmaf(c1[T], pig, (1.0f - eg) * pf);
                    const float ck  = num * __builtin_amdgcn_rcpf(pf * pig);
                    c1[T] = ck;
                    float carg = -2.0f * LOG2E * ck;
                    carg = fminf(fmaxf(carg, -80.0f), 80.0f);
                    const float ec = __builtin_amdgcn_exp2f(carg);
                    const float hk = (1.0f - ec) *
                                     __builtin_amdgcn_rcpf(po * (1.0f + ec));
                    const unsigned hbits = __float_as_uint(hk);
                    const float rem = hk - __uint_as_float(hbits & 0xffff0000u);
                    v = __builtin_amdgcn_perm(__float_as_uint(rem), hbits, 0x07060302u);
                } else if (u == 30) {
                    v = apk;                      // AVG[t+1] slot (wave1, T=3, quad=2)
                }
                hn[s * 36 + u] = v;               // u=31 lane writes 0 (pad)
            }
            __syncthreads();                      // h_t halves visible to both waves
        }
    }

    __syncthreads();
    // ---- coalesced flush: 16 seq x 120 t = 480 float4 by 128 threads ----
    float* outb = out + (size_t)blockIdx.x * 16 * 120;
#pragma unroll
    for (int it = 0; it < 4; it++) {
        const int fi = it * 128 + tid;
        if (fi < 480) {
            const int sq = fi / 30, j = fi % 30;
            const float4 v = *reinterpret_cast<const float4*>(&out_s[sq * 124 + j * 4]);
            *reinterpret_cast<float4*>(&outb[sq * 120 + j * 4]) = v;
        }
    }
}

extern "C" void kernel_launch(void* const* d_in, const int* in_sizes, int n_in,
                              void* d_out, int out_size, void* d_ws, size_t ws_size,
                              hipStream_t stream) {
    (void)in_sizes; (void)n_in; (void)out_size; (void)ws_size;
    const float* feat  = (const float*)d_in[0];
    const float* w_ih1 = (const float*)d_in[1];
    const float* w_hh1 = (const float*)d_in[2];
    const float* b1    = (const float*)d_in[3];
    const float* w_ih2 = (const float*)d_in[4];
    const float* w_hh2 = (const float*)d_in[5];
    const float* b2    = (const float*)d_in[6];
    float* ws  = (float*)d_ws;
    float* out = (float*)d_out;

    hipLaunchKernelGGL(pack_weights, dim3(1), dim3(256), 0, stream,
                       w_ih1, w_hh1, b1, w_ih2, b2, ws);
    hipLaunchKernelGGL(lstm_mfma_kernel, dim3(2048), dim3(128), 0, stream,
                       feat, w_hh2, ws, out);
}